// Round 5
// baseline (248.873 us; speedup 1.0000x reference)
//
#include <hip/hip_runtime.h>
#include <hip/hip_bf16.h>
#include <cstddef>

#define NN 50000
#define NR 8
#define NE 800000
#define DD 128
#define KTOT 1024          // NR * DD
#define NB (NN * NR)       // sort bins: key = dst*8 + rel
#define NSCAN ((NB + 1023) / 1024)   // 391
#define XPAD 136

typedef __bf16 bf16x8 __attribute__((ext_vector_type(8)));
typedef float  f32x4  __attribute__((ext_vector_type(4)));

// ---------------------------------------------------------------------------
// Phase A: counting sort of edges by key = dst*8 + rel
// ---------------------------------------------------------------------------
__global__ __launch_bounds__(256) void hist_kernel(
    const int* __restrict__ dst, const int* __restrict__ rel, int* __restrict__ cnt)
{
    int e = blockIdx.x * 256 + threadIdx.x;
    if (e < NE) atomicAdd(&cnt[dst[e] * NR + rel[e]], 1);
}

// 3-pass parallel exclusive scan over NB bins
__global__ __launch_bounds__(1024) void scan1_kernel(
    const int* __restrict__ cnt, int* __restrict__ offsets, int* __restrict__ blockSums)
{
    __shared__ int sm[1024];
    const int t = threadIdx.x;
    const int i = blockIdx.x * 1024 + t;
    const int v = (i < NB) ? cnt[i] : 0;
    sm[t] = v;
    __syncthreads();
    #pragma unroll
    for (int off = 1; off < 1024; off <<= 1) {
        int u = (t >= off) ? sm[t - off] : 0;
        __syncthreads();
        sm[t] += u;
        __syncthreads();
    }
    if (i < NB) offsets[i] = sm[t] - v;            // intra-block exclusive
    if (t == 1023) blockSums[blockIdx.x] = sm[1023];
}

__global__ __launch_bounds__(512) void scan2_kernel(int* __restrict__ blockSums)
{
    __shared__ int sm[512];
    const int t = threadIdx.x;
    const int v = (t < NSCAN) ? blockSums[t] : 0;
    sm[t] = v;
    __syncthreads();
    #pragma unroll
    for (int off = 1; off < 512; off <<= 1) {
        int u = (t >= off) ? sm[t - off] : 0;
        __syncthreads();
        sm[t] += u;
        __syncthreads();
    }
    if (t < NSCAN) blockSums[t] = sm[t] - v;       // exclusive base per block
}

__global__ __launch_bounds__(1024) void scan3_kernel(
    int* __restrict__ offsets, int* __restrict__ cursor, const int* __restrict__ blockSums)
{
    const int i = blockIdx.x * 1024 + threadIdx.x;
    if (i < NB) {
        const int o = offsets[i] + blockSums[blockIdx.x];
        offsets[i] = o;
        cursor[i]  = o;
    }
    if (blockIdx.x == 0 && threadIdx.x == 0) offsets[NB] = NE;
}

__global__ __launch_bounds__(256) void scatter_kernel(
    const int* __restrict__ src, const int* __restrict__ dst,
    const int* __restrict__ rel, int* __restrict__ cursor,
    unsigned* __restrict__ packed)
{
    int e = blockIdx.x * 256 + threadIdx.x;
    if (e < NE) {
        const int key = dst[e] * NR + rel[e];
        const int pos = atomicAdd(&cursor[key], 1);
        packed[pos] = (unsigned)src[e];
    }
}

// ---------------------------------------------------------------------------
// X -> bf16 conversion (12.8 MB)
// ---------------------------------------------------------------------------
__global__ __launch_bounds__(256) void xcvt_kernel(
    const float* __restrict__ X, __hip_bfloat16* __restrict__ Xb)
{
    const int i = blockIdx.x * 256 + threadIdx.x;   // one thread = 8 floats
    if (i >= NN * DD / 8) return;
    const float4* xp = (const float4*)(X + (size_t)i * 8);
    const float4 a = xp[0], b = xp[1];
    __bf16 h[8] = {(__bf16)a.x, (__bf16)a.y, (__bf16)a.z, (__bf16)a.w,
                   (__bf16)b.x, (__bf16)b.y, (__bf16)b.z, (__bf16)b.w};
    *(uint4*)(Xb + (size_t)i * 8) = *(uint4*)h;
}

// ---------------------------------------------------------------------------
// Phase B: segment-parallel aggregation. One wave per (node, rel) segment.
// A[n][r*128+:] = inv_norm[n,r] * sum_{e in seg} Xb[src[e], :]   (bf16)
// ---------------------------------------------------------------------------
__global__ __launch_bounds__(256) void agg_bf16_kernel(
    const __hip_bfloat16* __restrict__ Xb, const float* __restrict__ inv_norm,
    const int* __restrict__ offsets, const unsigned* __restrict__ packed,
    __hip_bfloat16* __restrict__ A)
{
    const int lane = threadIdx.x & 63;
    const int seg  = blockIdx.x * 4 + (threadIdx.x >> 6);   // key = n*8+r
    if (seg >= NB) return;
    const int node = seg >> 3, r = seg & 7;
    const int beg = offsets[seg], end = offsets[seg + 1];

    float sx = 0.f, sy = 0.f;
    int e = beg;
    for (; e + 2 <= end; e += 2) {
        const unsigned s0 = packed[e], s1 = packed[e + 1];
        const unsigned u0 = ((const unsigned*)(Xb + (size_t)s0 * DD))[lane];
        const unsigned u1 = ((const unsigned*)(Xb + (size_t)s1 * DD))[lane];
        sx += __uint_as_float(u0 << 16) + __uint_as_float(u1 << 16);
        sy += __uint_as_float(u0 & 0xFFFF0000u) + __uint_as_float(u1 & 0xFFFF0000u);
    }
    if (e < end) {
        const unsigned u0 = ((const unsigned*)(Xb + (size_t)packed[e] * DD))[lane];
        sx += __uint_as_float(u0 << 16);
        sy += __uint_as_float(u0 & 0xFFFF0000u);
    }
    const float inv = inv_norm[seg];
    __bf16 h[2] = {(__bf16)(sx * inv), (__bf16)(sy * inv)};
    ((unsigned*)(A + (size_t)node * KTOT + r * DD))[lane] = *(unsigned*)h;
}

// fp32-gather variant (used only if ws can't fit Xb)
__global__ __launch_bounds__(256) void agg_f32_kernel(
    const float* __restrict__ X, const float* __restrict__ inv_norm,
    const int* __restrict__ offsets, const unsigned* __restrict__ packed,
    __hip_bfloat16* __restrict__ A)
{
    const int lane = threadIdx.x & 63;
    const int seg  = blockIdx.x * 4 + (threadIdx.x >> 6);
    if (seg >= NB) return;
    const int node = seg >> 3, r = seg & 7;
    const int beg = offsets[seg], end = offsets[seg + 1];
    float sx = 0.f, sy = 0.f;
    for (int e = beg; e < end; ++e) {
        const float2 x = ((const float2*)(X + (size_t)packed[e] * DD))[lane];
        sx += x.x; sy += x.y;
    }
    const float inv = inv_norm[seg];
    __bf16 h[2] = {(__bf16)(sx * inv), (__bf16)(sy * inv)};
    ((unsigned*)(A + (size_t)node * KTOT + r * DD))[lane] = *(unsigned*)h;
}

// ---------------------------------------------------------------------------
// W transpose + bf16 convert:  Wt[c][n][k] = W[c][k][n]  (c==8 -> W0)
// ---------------------------------------------------------------------------
__global__ __launch_bounds__(256) void wcvt_kernel(
    const float* __restrict__ W, const float* __restrict__ W0,
    __hip_bfloat16* __restrict__ Wt)
{
    int idx = blockIdx.x * 256 + threadIdx.x;
    if (idx >= 9 * DD * DD) return;
    const int c = idx >> 14;
    const int r = idx & 16383;
    const int n = r >> 7, k = r & 127;
    const float v = (c < NR) ? W[(size_t)c * DD * DD + k * DD + n] : W0[k * DD + n];
    Wt[idx] = __float2bfloat16(v);
}

// ---------------------------------------------------------------------------
// Phase C: out = [A | Xb] @ [Wt stack]   (K = 1152 as 9 chunks of 128)
// 128x128 tile, 4 waves (2x2), mfma_f32_16x16x32_bf16, 4x4 frags/wave.
// LDS rows 256B, XOR-swizzle byte ^= (row&7)<<4 (T2).
// ---------------------------------------------------------------------------
template <bool USEXB>
__global__ __launch_bounds__(256) void mfma_gemm_kernel(
    const __hip_bfloat16* __restrict__ A, const float* __restrict__ X,
    const __hip_bfloat16* __restrict__ Xb,
    const __hip_bfloat16* __restrict__ Wt, float* __restrict__ out)
{
    __shared__ __align__(16) char As[128 * 256];
    __shared__ __align__(16) char Bs[128 * 256];

    const int tid  = threadIdx.x;
    const int n0   = blockIdx.x * 128;
    const int lane = tid & 63;
    const int wid  = tid >> 6;
    const int wr   = wid >> 1, wc = wid & 1;
    const int l15  = lane & 15, kg = lane >> 4;

    f32x4 acc[4][4];
    #pragma unroll
    for (int mf = 0; mf < 4; ++mf)
        #pragma unroll
        for (int nf = 0; nf < 4; ++nf)
            acc[mf][nf] = (f32x4){0.f, 0.f, 0.f, 0.f};

    for (int c = 0; c < NR + 1; ++c) {
        if (c < NR) {
            #pragma unroll
            for (int it = 0; it < 8; ++it) {
                const int idx = tid + it * 256;
                const int row = idx >> 4, b = idx & 15;
                const int n = n0 + row;
                uint4 v = make_uint4(0u, 0u, 0u, 0u);
                if (n < NN)
                    v = *(const uint4*)(A + (size_t)n * KTOT + c * DD + b * 8);
                *(uint4*)(As + row * 256 + ((b ^ (row & 7)) << 4)) = v;
            }
        } else if constexpr (USEXB) {
            #pragma unroll
            for (int it = 0; it < 8; ++it) {
                const int idx = tid + it * 256;
                const int row = idx >> 4, b = idx & 15;
                const int n = n0 + row;
                uint4 v = make_uint4(0u, 0u, 0u, 0u);
                if (n < NN)
                    v = *(const uint4*)(Xb + (size_t)n * DD + b * 8);
                *(uint4*)(As + row * 256 + ((b ^ (row & 7)) << 4)) = v;
            }
        } else {
            #pragma unroll
            for (int it = 0; it < 8; ++it) {
                const int idx = tid + it * 256;
                const int row = idx >> 4, b = idx & 15;
                const int n = n0 + row;
                float4 f0 = make_float4(0.f,0.f,0.f,0.f), f1 = f0;
                if (n < NN) {
                    const float4* xp = (const float4*)(X + (size_t)n * DD);
                    f0 = xp[b * 2];
                    f1 = xp[b * 2 + 1];
                }
                __bf16 h[8] = {(__bf16)f0.x, (__bf16)f0.y, (__bf16)f0.z, (__bf16)f0.w,
                               (__bf16)f1.x, (__bf16)f1.y, (__bf16)f1.z, (__bf16)f1.w};
                *(uint4*)(As + row * 256 + ((b ^ (row & 7)) << 4)) = *(uint4*)h;
            }
        }
        // ---- stage B chunk: Wt[c] is [n][k] row-major bf16 ----
        {
            const __hip_bfloat16* Wc = Wt + (size_t)c * DD * DD;
            #pragma unroll
            for (int it = 0; it < 8; ++it) {
                const int idx = tid + it * 256;
                const int row = idx >> 4, b = idx & 15;
                const uint4 v = *(const uint4*)(Wc + (size_t)row * DD + b * 8);
                *(uint4*)(Bs + row * 256 + ((b ^ (row & 7)) << 4)) = v;
            }
        }
        __syncthreads();

        #pragma unroll
        for (int ks = 0; ks < 4; ++ks) {
            const int b = ks * 4 + kg;
            bf16x8 af[4], bfr[4];
            #pragma unroll
            for (int mf = 0; mf < 4; ++mf) {
                const int row = wr * 64 + mf * 16 + l15;
                af[mf] = *(const bf16x8*)(As + row * 256 + ((b ^ (row & 7)) << 4));
            }
            #pragma unroll
            for (int nf = 0; nf < 4; ++nf) {
                const int row = wc * 64 + nf * 16 + l15;
                bfr[nf] = *(const bf16x8*)(Bs + row * 256 + ((b ^ (row & 7)) << 4));
            }
            #pragma unroll
            for (int mf = 0; mf < 4; ++mf)
                #pragma unroll
                for (int nf = 0; nf < 4; ++nf)
                    acc[mf][nf] = __builtin_amdgcn_mfma_f32_16x16x32_bf16(
                        af[mf], bfr[nf], acc[mf][nf], 0, 0, 0);
        }
        __syncthreads();
    }

    // epilogue: C/D layout col=lane&15, row=(lane>>4)*4+reg  [m89/m91]
    #pragma unroll
    for (int mf = 0; mf < 4; ++mf) {
        #pragma unroll
        for (int reg = 0; reg < 4; ++reg) {
            const int n = n0 + wr * 64 + mf * 16 + kg * 4 + reg;
            if (n < NN) {
                #pragma unroll
                for (int nf = 0; nf < 4; ++nf)
                    out[(size_t)n * DD + wc * 64 + nf * 16 + l15] = acc[mf][nf][reg];
            }
        }
    }
}

// ---------------------------------------------------------------------------
// Fallback (ws too small)
// ---------------------------------------------------------------------------
__global__ __launch_bounds__(256) void xform0_kernel(
    const float* __restrict__ X, const float* __restrict__ W0, float* __restrict__ out)
{
    __shared__ __align__(16) float Xs[64][XPAD];
    const int n0 = blockIdx.x * 64;
    const int tid = threadIdx.x;
    for (int t = tid; t < 64 * 32; t += 256) {
        const int row = t >> 5, g = t & 31;
        const int n = n0 + row;
        float4 v = make_float4(0.f, 0.f, 0.f, 0.f);
        if (n < NN) v = ((const float4*)(X + (size_t)n * DD))[g];
        *(float4*)&Xs[row][g * 4] = v;
    }
    __syncthreads();
    const int to = tid & 31, tn = tid >> 5;
    float acc[8][4];
    #pragma unroll
    for (int k = 0; k < 8; ++k)
        #pragma unroll
        for (int j = 0; j < 4; ++j) acc[k][j] = 0.f;
    for (int i = 0; i < DD; ++i) {
        const float4 w = ((const float4*)(W0 + (size_t)i * DD))[to];
        #pragma unroll
        for (int k = 0; k < 8; ++k) {
            const float xs = Xs[tn * 8 + k][i];
            acc[k][0] += xs * w.x; acc[k][1] += xs * w.y;
            acc[k][2] += xs * w.z; acc[k][3] += xs * w.w;
        }
    }
    #pragma unroll
    for (int k = 0; k < 8; ++k) {
        const int n = n0 + tn * 8 + k;
        if (n < NN)
            ((float4*)(out + (size_t)n * DD))[to] =
                make_float4(acc[k][0], acc[k][1], acc[k][2], acc[k][3]);
    }
}

__global__ __launch_bounds__(128) void edge_fallback_kernel(
    const float* __restrict__ X, const float* __restrict__ W,
    const float* __restrict__ inv_norm,
    const int* __restrict__ src, const int* __restrict__ dst,
    const int* __restrict__ rel, float* __restrict__ out)
{
    const int o = threadIdx.x;
    for (int e = blockIdx.x; e < NE; e += gridDim.x) {
        const int s = src[e], d = dst[e], r = rel[e];
        const float inv = inv_norm[(size_t)d * NR + r];
        const float* Xr = X + (size_t)s * DD;
        const float* Wr = W + (size_t)r * DD * DD;
        float a = 0.f;
        for (int i = 0; i < DD; ++i) a += Xr[i] * Wr[i * DD + o];
        unsafeAtomicAdd(out + (size_t)d * DD + o, a * inv);
    }
}

// ---------------------------------------------------------------------------
extern "C" void kernel_launch(void* const* d_in, const int* in_sizes, int n_in,
                              void* d_out, int out_size, void* d_ws, size_t ws_size,
                              hipStream_t stream)
{
    const float* X        = (const float*)d_in[0];
    const float* W        = (const float*)d_in[1];
    const float* W0       = (const float*)d_in[2];
    const float* inv_norm = (const float*)d_in[3];
    const int*   src      = (const int*)d_in[4];
    const int*   dst      = (const int*)d_in[5];
    const int*   rel      = (const int*)d_in[6];
    float* out = (float*)d_out;

    char* ws = (char*)d_ws;
    size_t off = 0;
    auto alloc = [&](size_t bytes) {
        void* p = ws + off;
        off += (bytes + 255) & ~(size_t)255;
        return p;
    };
    __hip_bfloat16* A  = (__hip_bfloat16*)alloc((size_t)NN * KTOT * sizeof(__hip_bfloat16));
    int*      offsets  = (int*)alloc((size_t)(NB + 1) * sizeof(int));
    int*      cursor   = (int*)alloc((size_t)NB * sizeof(int));
    int*      cnt      = (int*)alloc((size_t)NB * sizeof(int));
    unsigned* packed   = (unsigned*)alloc((size_t)NE * sizeof(unsigned));
    __hip_bfloat16* Wt = (__hip_bfloat16*)alloc((size_t)9 * DD * DD * sizeof(__hip_bfloat16));
    int*    blockSums  = (int*)alloc((size_t)NSCAN * sizeof(int));
    const size_t need_base = off;
    __hip_bfloat16* Xb = (__hip_bfloat16*)alloc((size_t)NN * DD * sizeof(__hip_bfloat16));
    const size_t need_full = off;

    if (ws_size >= need_base) {
        hipMemsetAsync(cnt, 0, (size_t)NB * sizeof(int), stream);
        hist_kernel<<<(NE + 255) / 256, 256, 0, stream>>>(dst, rel, cnt);
        scan1_kernel<<<NSCAN, 1024, 0, stream>>>(cnt, offsets, blockSums);
        scan2_kernel<<<1, 512, 0, stream>>>(blockSums);
        scan3_kernel<<<NSCAN, 1024, 0, stream>>>(offsets, cursor, blockSums);
        scatter_kernel<<<(NE + 255) / 256, 256, 0, stream>>>(src, dst, rel, cursor, packed);
        wcvt_kernel<<<(9 * DD * DD + 255) / 256, 256, 0, stream>>>(W, W0, Wt);
        if (ws_size >= need_full) {
            xcvt_kernel<<<(NN * DD / 8 + 255) / 256, 256, 0, stream>>>(X, Xb);
            agg_bf16_kernel<<<(NB + 3) / 4, 256, 0, stream>>>(Xb, inv_norm, offsets, packed, A);
            mfma_gemm_kernel<true><<<(NN + 127) / 128, 256, 0, stream>>>(A, X, Xb, Wt, out);
        } else {
            agg_f32_kernel<<<(NB + 3) / 4, 256, 0, stream>>>(X, inv_norm, offsets, packed, A);
            mfma_gemm_kernel<false><<<(NN + 127) / 128, 256, 0, stream>>>(A, X, Xb, Wt, out);
        }
    } else {
        xform0_kernel<<<(NN + 63) / 64, 256, 0, stream>>>(X, W0, out);
        edge_fallback_kernel<<<8192, 128, 0, stream>>>(X, W, inv_norm, src, dst, rel, out);
    }
}

// Round 6
// 193.433 us; speedup vs baseline: 1.2866x; 1.2866x over previous
//
#include <hip/hip_runtime.h>
#include <hip/hip_bf16.h>
#include <cstddef>

#define NN 50000
#define NR 8
#define NE 800000
#define DD 128
#define KTOT 1024          // NR * DD
#define NB (NN * NR)       // sort bins: key = dst*8 + rel
#define NSCAN ((NB + 1023) / 1024)   // 391
#define XPAD 136

typedef __bf16 bf16x8 __attribute__((ext_vector_type(8)));
typedef float  f32x4  __attribute__((ext_vector_type(4)));

// ---------------------------------------------------------------------------
// Phase A: counting sort of edges by key = dst*8 + rel
// ---------------------------------------------------------------------------
__global__ __launch_bounds__(256) void hist_kernel(
    const int* __restrict__ dst, const int* __restrict__ rel, int* __restrict__ cnt)
{
    int e = blockIdx.x * 256 + threadIdx.x;
    if (e < NE) atomicAdd(&cnt[dst[e] * NR + rel[e]], 1);
}

// 3-pass parallel exclusive scan over NB bins
__global__ __launch_bounds__(1024) void scan1_kernel(
    const int* __restrict__ cnt, int* __restrict__ offsets, int* __restrict__ blockSums)
{
    __shared__ int sm[1024];
    const int t = threadIdx.x;
    const int i = blockIdx.x * 1024 + t;
    const int v = (i < NB) ? cnt[i] : 0;
    sm[t] = v;
    __syncthreads();
    #pragma unroll
    for (int off = 1; off < 1024; off <<= 1) {
        int u = (t >= off) ? sm[t - off] : 0;
        __syncthreads();
        sm[t] += u;
        __syncthreads();
    }
    if (i < NB) offsets[i] = sm[t] - v;            // intra-block exclusive
    if (t == 1023) blockSums[blockIdx.x] = sm[1023];
}

__global__ __launch_bounds__(512) void scan2_kernel(int* __restrict__ blockSums)
{
    __shared__ int sm[512];
    const int t = threadIdx.x;
    const int v = (t < NSCAN) ? blockSums[t] : 0;
    sm[t] = v;
    __syncthreads();
    #pragma unroll
    for (int off = 1; off < 512; off <<= 1) {
        int u = (t >= off) ? sm[t - off] : 0;
        __syncthreads();
        sm[t] += u;
        __syncthreads();
    }
    if (t < NSCAN) blockSums[t] = sm[t] - v;       // exclusive base per block
}

__global__ __launch_bounds__(1024) void scan3_kernel(
    int* __restrict__ offsets, int* __restrict__ cursor, const int* __restrict__ blockSums)
{
    const int i = blockIdx.x * 1024 + threadIdx.x;
    if (i < NB) {
        const int o = offsets[i] + blockSums[blockIdx.x];
        offsets[i] = o;
        cursor[i]  = o;
    }
    if (blockIdx.x == 0 && threadIdx.x == 0) offsets[NB] = NE;
}

__global__ __launch_bounds__(256) void scatter_kernel(
    const int* __restrict__ src, const int* __restrict__ dst,
    const int* __restrict__ rel, int* __restrict__ cursor,
    unsigned* __restrict__ packed)
{
    int e = blockIdx.x * 256 + threadIdx.x;
    if (e < NE) {
        const int key = dst[e] * NR + rel[e];
        const int pos = atomicAdd(&cursor[key], 1);
        packed[pos] = (unsigned)src[e];
    }
}

// ---------------------------------------------------------------------------
// Combined conversion: X -> Xb (bf16, 12.8 MB) and W/W0 -> Wt (transposed bf16)
// ---------------------------------------------------------------------------
#define NXCVT (NN * DD / 8)          // 800000 threads, 8 floats each
#define NWCVT (9 * DD * DD)          // 147456 threads, 1 elem each
__global__ __launch_bounds__(256) void cvt_kernel(
    const float* __restrict__ X, __hip_bfloat16* __restrict__ Xb,
    const float* __restrict__ W, const float* __restrict__ W0,
    __hip_bfloat16* __restrict__ Wt)
{
    const int i = blockIdx.x * 256 + threadIdx.x;
    if (i < NXCVT) {
        const float4* xp = (const float4*)(X + (size_t)i * 8);
        const float4 a = xp[0], b = xp[1];
        __bf16 h[8] = {(__bf16)a.x, (__bf16)a.y, (__bf16)a.z, (__bf16)a.w,
                       (__bf16)b.x, (__bf16)b.y, (__bf16)b.z, (__bf16)b.w};
        *(uint4*)(Xb + (size_t)i * 8) = *(uint4*)h;
    } else {
        const int idx = i - NXCVT;
        if (idx < NWCVT) {
            const int c = idx >> 14;
            const int r = idx & 16383;
            const int n = r >> 7, k = r & 127;
            const float v = (c < NR) ? W[(size_t)c * DD * DD + k * DD + n]
                                     : W0[k * DD + n];
            Wt[idx] = __float2bfloat16(v);
        }
    }
}

// ---------------------------------------------------------------------------
// Phase B: quarter-wave segment aggregation. Each 16-lane quarter owns one
// (node,rel) segment; 4 independent gather chains per wave (8 loads in
// flight with unroll-2). Row = 128 bf16 = 256 B = 16 lanes x uint4.
// A[n][r*128+:] = inv_norm[n,r] * sum_{e in seg} Xb[src[e], :]   (bf16)
// ---------------------------------------------------------------------------
__device__ __forceinline__ void accum8(float* acc, const uint4 u)
{
    const unsigned w[4] = {u.x, u.y, u.z, u.w};
    #pragma unroll
    for (int j = 0; j < 4; ++j) {
        acc[2 * j]     += __uint_as_float(w[j] << 16);
        acc[2 * j + 1] += __uint_as_float(w[j] & 0xFFFF0000u);
    }
}

__global__ __launch_bounds__(256) void agg_bf16_kernel(
    const __hip_bfloat16* __restrict__ Xb, const float* __restrict__ inv_norm,
    const int* __restrict__ offsets, const unsigned* __restrict__ packed,
    __hip_bfloat16* __restrict__ A)
{
    const int tid  = threadIdx.x;
    const int lane = tid & 63;
    const int q    = lane >> 4;                      // quarter 0..3
    const int l    = lane & 15;                      // lane within quarter
    const int wave = blockIdx.x * 4 + (tid >> 6);
    const int seg  = wave * 4 + q;                   // NB = 400000 = 4*100000 exact
    if (seg >= NB) return;

    const int beg = offsets[seg];
    const int end = offsets[seg + 1];

    float acc[8] = {0.f, 0.f, 0.f, 0.f, 0.f, 0.f, 0.f, 0.f};
    int e = beg;
    for (; e + 2 <= end; e += 2) {
        const unsigned s0 = packed[e];
        const unsigned s1 = packed[e + 1];
        const uint4 u0 = *(const uint4*)(Xb + (size_t)s0 * DD + l * 8);
        const uint4 u1 = *(const uint4*)(Xb + (size_t)s1 * DD + l * 8);
        accum8(acc, u0);
        accum8(acc, u1);
    }
    if (e < end) {
        const uint4 u0 = *(const uint4*)(Xb + (size_t)packed[e] * DD + l * 8);
        accum8(acc, u0);
    }

    const float inv = inv_norm[seg];
    __bf16 h[8];
    #pragma unroll
    for (int j = 0; j < 8; ++j) h[j] = (__bf16)(acc[j] * inv);
    const int node = seg >> 3, r = seg & 7;
    *(uint4*)(A + (size_t)node * KTOT + r * DD + l * 8) = *(uint4*)h;
}

// fp32-gather variant (used only if ws can't fit Xb)
__global__ __launch_bounds__(256) void agg_f32_kernel(
    const float* __restrict__ X, const float* __restrict__ inv_norm,
    const int* __restrict__ offsets, const unsigned* __restrict__ packed,
    __hip_bfloat16* __restrict__ A)
{
    const int lane = threadIdx.x & 63;
    const int seg  = blockIdx.x * 4 + (threadIdx.x >> 6);
    if (seg >= NB) return;
    const int node = seg >> 3, r = seg & 7;
    const int beg = offsets[seg], end = offsets[seg + 1];
    float sx = 0.f, sy = 0.f;
    for (int e = beg; e < end; ++e) {
        const float2 x = ((const float2*)(X + (size_t)packed[e] * DD))[lane];
        sx += x.x; sy += x.y;
    }
    const float inv = inv_norm[seg];
    __bf16 h[2] = {(__bf16)(sx * inv), (__bf16)(sy * inv)};
    ((unsigned*)(A + (size_t)node * KTOT + r * DD))[lane] = *(unsigned*)h;
}

// ---------------------------------------------------------------------------
// Phase C: out = [A | Xb] @ [Wt stack]   (K = 1152 as 9 chunks of 128)
// 128x128 tile, 4 waves (2x2), mfma_f32_16x16x32_bf16, 4x4 frags/wave.
// LDS rows 256B, XOR-swizzle byte ^= (row&7)<<4 (T2).
// ---------------------------------------------------------------------------
template <bool USEXB>
__global__ __launch_bounds__(256) void mfma_gemm_kernel(
    const __hip_bfloat16* __restrict__ A, const float* __restrict__ X,
    const __hip_bfloat16* __restrict__ Xb,
    const __hip_bfloat16* __restrict__ Wt, float* __restrict__ out)
{
    __shared__ __align__(16) char As[128 * 256];
    __shared__ __align__(16) char Bs[128 * 256];

    const int tid  = threadIdx.x;
    const int n0   = blockIdx.x * 128;
    const int lane = tid & 63;
    const int wid  = tid >> 6;
    const int wr   = wid >> 1, wc = wid & 1;
    const int l15  = lane & 15, kg = lane >> 4;

    f32x4 acc[4][4];
    #pragma unroll
    for (int mf = 0; mf < 4; ++mf)
        #pragma unroll
        for (int nf = 0; nf < 4; ++nf)
            acc[mf][nf] = (f32x4){0.f, 0.f, 0.f, 0.f};

    for (int c = 0; c < NR + 1; ++c) {
        if (c < NR) {
            #pragma unroll
            for (int it = 0; it < 8; ++it) {
                const int idx = tid + it * 256;
                const int row = idx >> 4, b = idx & 15;
                const int n = n0 + row;
                uint4 v = make_uint4(0u, 0u, 0u, 0u);
                if (n < NN)
                    v = *(const uint4*)(A + (size_t)n * KTOT + c * DD + b * 8);
                *(uint4*)(As + row * 256 + ((b ^ (row & 7)) << 4)) = v;
            }
        } else if constexpr (USEXB) {
            #pragma unroll
            for (int it = 0; it < 8; ++it) {
                const int idx = tid + it * 256;
                const int row = idx >> 4, b = idx & 15;
                const int n = n0 + row;
                uint4 v = make_uint4(0u, 0u, 0u, 0u);
                if (n < NN)
                    v = *(const uint4*)(Xb + (size_t)n * DD + b * 8);
                *(uint4*)(As + row * 256 + ((b ^ (row & 7)) << 4)) = v;
            }
        } else {
            #pragma unroll
            for (int it = 0; it < 8; ++it) {
                const int idx = tid + it * 256;
                const int row = idx >> 4, b = idx & 15;
                const int n = n0 + row;
                float4 f0 = make_float4(0.f,0.f,0.f,0.f), f1 = f0;
                if (n < NN) {
                    const float4* xp = (const float4*)(X + (size_t)n * DD);
                    f0 = xp[b * 2];
                    f1 = xp[b * 2 + 1];
                }
                __bf16 h[8] = {(__bf16)f0.x, (__bf16)f0.y, (__bf16)f0.z, (__bf16)f0.w,
                               (__bf16)f1.x, (__bf16)f1.y, (__bf16)f1.z, (__bf16)f1.w};
                *(uint4*)(As + row * 256 + ((b ^ (row & 7)) << 4)) = *(uint4*)h;
            }
        }
        // ---- stage B chunk: Wt[c] is [n][k] row-major bf16 ----
        {
            const __hip_bfloat16* Wc = Wt + (size_t)c * DD * DD;
            #pragma unroll
            for (int it = 0; it < 8; ++it) {
                const int idx = tid + it * 256;
                const int row = idx >> 4, b = idx & 15;
                const uint4 v = *(const uint4*)(Wc + (size_t)row * DD + b * 8);
                *(uint4*)(Bs + row * 256 + ((b ^ (row & 7)) << 4)) = v;
            }
        }
        __syncthreads();

        #pragma unroll
        for (int ks = 0; ks < 4; ++ks) {
            const int b = ks * 4 + kg;
            bf16x8 af[4], bfr[4];
            #pragma unroll
            for (int mf = 0; mf < 4; ++mf) {
                const int row = wr * 64 + mf * 16 + l15;
                af[mf] = *(const bf16x8*)(As + row * 256 + ((b ^ (row & 7)) << 4));
            }
            #pragma unroll
            for (int nf = 0; nf < 4; ++nf) {
                const int row = wc * 64 + nf * 16 + l15;
                bfr[nf] = *(const bf16x8*)(Bs + row * 256 + ((b ^ (row & 7)) << 4));
            }
            #pragma unroll
            for (int mf = 0; mf < 4; ++mf)
                #pragma unroll
                for (int nf = 0; nf < 4; ++nf)
                    acc[mf][nf] = __builtin_amdgcn_mfma_f32_16x16x32_bf16(
                        af[mf], bfr[nf], acc[mf][nf], 0, 0, 0);
        }
        __syncthreads();
    }

    // epilogue: C/D layout col=lane&15, row=(lane>>4)*4+reg  [m89/m91]
    #pragma unroll
    for (int mf = 0; mf < 4; ++mf) {
        #pragma unroll
        for (int reg = 0; reg < 4; ++reg) {
            const int n = n0 + wr * 64 + mf * 16 + kg * 4 + reg;
            if (n < NN) {
                #pragma unroll
                for (int nf = 0; nf < 4; ++nf)
                    out[(size_t)n * DD + wc * 64 + nf * 16 + l15] = acc[mf][nf][reg];
            }
        }
    }
}

// ---------------------------------------------------------------------------
// Fallback (ws too small)
// ---------------------------------------------------------------------------
__global__ __launch_bounds__(256) void xform0_kernel(
    const float* __restrict__ X, const float* __restrict__ W0, float* __restrict__ out)
{
    __shared__ __align__(16) float Xs[64][XPAD];
    const int n0 = blockIdx.x * 64;
    const int tid = threadIdx.x;
    for (int t = tid; t < 64 * 32; t += 256) {
        const int row = t >> 5, g = t & 31;
        const int n = n0 + row;
        float4 v = make_float4(0.f, 0.f, 0.f, 0.f);
        if (n < NN) v = ((const float4*)(X + (size_t)n * DD))[g];
        *(float4*)&Xs[row][g * 4] = v;
    }
    __syncthreads();
    const int to = tid & 31, tn = tid >> 5;
    float acc[8][4];
    #pragma unroll
    for (int k = 0; k < 8; ++k)
        #pragma unroll
        for (int j = 0; j < 4; ++j) acc[k][j] = 0.f;
    for (int i = 0; i < DD; ++i) {
        const float4 w = ((const float4*)(W0 + (size_t)i * DD))[to];
        #pragma unroll
        for (int k = 0; k < 8; ++k) {
            const float xs = Xs[tn * 8 + k][i];
            acc[k][0] += xs * w.x; acc[k][1] += xs * w.y;
            acc[k][2] += xs * w.z; acc[k][3] += xs * w.w;
        }
    }
    #pragma unroll
    for (int k = 0; k < 8; ++k) {
        const int n = n0 + tn * 8 + k;
        if (n < NN)
            ((float4*)(out + (size_t)n * DD))[to] =
                make_float4(acc[k][0], acc[k][1], acc[k][2], acc[k][3]);
    }
}

__global__ __launch_bounds__(128) void edge_fallback_kernel(
    const float* __restrict__ X, const float* __restrict__ W,
    const float* __restrict__ inv_norm,
    const int* __restrict__ src, const int* __restrict__ dst,
    const int* __restrict__ rel, float* __restrict__ out)
{
    const int o = threadIdx.x;
    for (int e = blockIdx.x; e < NE; e += gridDim.x) {
        const int s = src[e], d = dst[e], r = rel[e];
        const float inv = inv_norm[(size_t)d * NR + r];
        const float* Xr = X + (size_t)s * DD;
        const float* Wr = W + (size_t)r * DD * DD;
        float a = 0.f;
        for (int i = 0; i < DD; ++i) a += Xr[i] * Wr[i * DD + o];
        unsafeAtomicAdd(out + (size_t)d * DD + o, a * inv);
    }
}

// ---------------------------------------------------------------------------
extern "C" void kernel_launch(void* const* d_in, const int* in_sizes, int n_in,
                              void* d_out, int out_size, void* d_ws, size_t ws_size,
                              hipStream_t stream)
{
    const float* X        = (const float*)d_in[0];
    const float* W        = (const float*)d_in[1];
    const float* W0       = (const float*)d_in[2];
    const float* inv_norm = (const float*)d_in[3];
    const int*   src      = (const int*)d_in[4];
    const int*   dst      = (const int*)d_in[5];
    const int*   rel      = (const int*)d_in[6];
    float* out = (float*)d_out;

    char* ws = (char*)d_ws;
    size_t off = 0;
    auto alloc = [&](size_t bytes) {
        void* p = ws + off;
        off += (bytes + 255) & ~(size_t)255;
        return p;
    };
    __hip_bfloat16* A  = (__hip_bfloat16*)alloc((size_t)NN * KTOT * sizeof(__hip_bfloat16));
    int*      offsets  = (int*)alloc((size_t)(NB + 1) * sizeof(int));
    int*      cursor   = (int*)alloc((size_t)NB * sizeof(int));
    int*      cnt      = (int*)alloc((size_t)NB * sizeof(int));
    unsigned* packed   = (unsigned*)alloc((size_t)NE * sizeof(unsigned));
    __hip_bfloat16* Wt = (__hip_bfloat16*)alloc((size_t)9 * DD * DD * sizeof(__hip_bfloat16));
    int*    blockSums  = (int*)alloc((size_t)NSCAN * sizeof(int));
    const size_t need_base = off;
    __hip_bfloat16* Xb = (__hip_bfloat16*)alloc((size_t)NN * DD * sizeof(__hip_bfloat16));
    const size_t need_full = off;

    if (ws_size >= need_base) {
        hipMemsetAsync(cnt, 0, (size_t)NB * sizeof(int), stream);
        hist_kernel<<<(NE + 255) / 256, 256, 0, stream>>>(dst, rel, cnt);
        scan1_kernel<<<NSCAN, 1024, 0, stream>>>(cnt, offsets, blockSums);
        scan2_kernel<<<1, 512, 0, stream>>>(blockSums);
        scan3_kernel<<<NSCAN, 1024, 0, stream>>>(offsets, cursor, blockSums);
        scatter_kernel<<<(NE + 255) / 256, 256, 0, stream>>>(src, dst, rel, cursor, packed);
        if (ws_size >= need_full) {
            cvt_kernel<<<(NXCVT + NWCVT + 255) / 256, 256, 0, stream>>>(X, Xb, W, W0, Wt);
            agg_bf16_kernel<<<NB / 16, 256, 0, stream>>>(Xb, inv_norm, offsets, packed, A);
            mfma_gemm_kernel<true><<<(NN + 127) / 128, 256, 0, stream>>>(A, X, Xb, Wt, out);
        } else {
            cvt_kernel<<<(NXCVT + NWCVT + 255) / 256, 256, 0, stream>>>(X, Xb, W, W0, Wt);
            agg_f32_kernel<<<(NB + 3) / 4, 256, 0, stream>>>(X, inv_norm, offsets, packed, A);
            mfma_gemm_kernel<false><<<(NN + 127) / 128, 256, 0, stream>>>(A, X, Xb, Wt, out);
        }
    } else {
        xform0_kernel<<<(NN + 63) / 64, 256, 0, stream>>>(X, W0, out);
        edge_fallback_kernel<<<8192, 128, 0, stream>>>(X, W, inv_norm, src, dst, rel, out);
    }
}